// Round 1
// baseline (250.279 us; speedup 1.0000x reference)
//
#include <hip/hip_runtime.h>

// EMA along T for x[B=8, T=4096, F=1024] fp32.
// y_t = a*y_{t-1} + (1-a)*x_t, a=0.9, y_{-1}=0.
//
// Strategy: chunked scan with truncated warm-up. alpha^64 ~ 1.2e-3, so a
// thread starting its chunk reconstructs the carry by scanning only the
// previous W=64 timesteps (error <= 0.9^64 * max|y| ~ 2e-3; threshold 2.58e-2).
//
// v2 change vs the 243 us kernel: L 128 -> 64. The old version was
// latency-bound (Occupancy 9.5%, 2.6 TB/s, VALUBusy 2.3%): only 4 waves/CU
// issuing ~8 outstanding 1 KiB loads each. Halving L doubles the grid to
// 512 blocks -> 8 waves/CU co-resident -> 2x memory-level parallelism.
// Read amplification becomes 2x, but with L == W chunk k+1's warm-up reads
// are byte-identical to chunk k's main reads and run concurrently, so an
// XCD swizzle (all 16 chunk-blocks of one (b,fg) stream share one XCD)
// turns them into L2 hits: HBM traffic stays ~input+output.
//
// Thread = (b, f4, chunk): f4 indexes float4 groups along F (F4=256).
// Wave = 64 consecutive f4 at same t -> 1 KiB contiguous per load instr.
// Grid: 512 blocks x 256 thr = 2048 waves = 8 waves/CU.

using f4 = __attribute__((ext_vector_type(4))) float;

constexpr int Bn = 8;
constexpr int Tn = 4096;
constexpr int F4 = 256;        // 1024 floats / 4
constexpr int L  = 64;         // outputs per thread
constexpr int W  = 64;         // warm-up steps (0.9^64 ~ 1.18e-3)
constexpr float A   = 0.9f;
constexpr float OMA = 0.1f;    // 1 - alpha

__global__ __launch_bounds__(256) void ema_kernel(const f4* __restrict__ x,
                                                  f4* __restrict__ y) {
    const int tid          = threadIdx.x;
    const int lane_f       = tid & 63;        // f4 within group (wave-contig)
    const int chunk_in_blk = tid >> 6;        // 0..3 (wave-uniform)

    // XCD swizzle: dispatch round-robins blockIdx%8 across XCDs. Pin all 16
    // chunk-blocks of a stream p=(b,fg) to XCD p&7 so warm-up reads hit the
    // same L2 that the previous chunk's main reads are streaming through.
    const int blk      = blockIdx.x;          // 0..511
    const int xcd      = blk & 7;
    const int slot     = blk >> 3;            // 0..63
    const int chunkgrp = slot & 15;           // 0..15
    const int p        = ((slot >> 4) << 3) | xcd;   // stream id 0..31
    const int fg       = p & 3;               // 4 f-groups
    const int b        = p >> 2;              // 8 batches

    const int chunk = chunkgrp * 4 + chunk_in_blk;   // 0..63
    const int f4i   = (fg << 6) + lane_f;            // 0..255
    const int t0    = chunk * L;

    const f4* __restrict__ xp = x + (size_t)b * Tn * F4 + f4i;
    f4*       __restrict__ yp = y + (size_t)b * Tn * F4 + f4i;

    float ax = 0.f, ay = 0.f, az = 0.f, aw = 0.f;

    if (chunk > 0) {   // wave-uniform branch
        int idx = (t0 - W) * F4;
        #pragma unroll 8
        for (int i = 0; i < W; ++i) {
            f4 v = xp[idx];
            idx += F4;
            ax = fmaf(A, ax, OMA * v.x);
            ay = fmaf(A, ay, OMA * v.y);
            az = fmaf(A, az, OMA * v.z);
            aw = fmaf(A, aw, OMA * v.w);
        }
    }

    int idx = t0 * F4;
    #pragma unroll 8
    for (int i = 0; i < L; ++i) {
        f4 v = xp[idx];
        ax = fmaf(A, ax, OMA * v.x);
        ay = fmaf(A, ay, OMA * v.y);
        az = fmaf(A, az, OMA * v.z);
        aw = fmaf(A, aw, OMA * v.w);
        f4 o;
        o.x = ax; o.y = ay; o.z = az; o.w = aw;
        __builtin_nontemporal_store(o, yp + idx);
        idx += F4;
    }
}

extern "C" void kernel_launch(void* const* d_in, const int* in_sizes, int n_in,
                              void* d_out, int out_size, void* d_ws, size_t ws_size,
                              hipStream_t stream) {
    const f4* x = (const f4*)d_in[0];
    f4*       y = (f4*)d_out;
    dim3 grid(Bn * 4 * 16);  // 512 blocks (8 b x 4 fg x 16 chunkgroups)
    dim3 block(256);
    ema_kernel<<<grid, block, 0, stream>>>(x, y);
}

// Round 2
// 243.949 us; speedup vs baseline: 1.0259x; 1.0259x over previous
//
#include <hip/hip_runtime.h>

// EMA along T for x[B=8, T=4096, F=1024] fp32.
// y_t = a*y_{t-1} + (1-a)*x_t, a=0.9, y_{-1}=0.
//
// Chunked scan with truncated warm-up (W=64; 0.9^64 ~ 1.2e-3 << 2.58e-2
// threshold). Thread = (b, f4, chunk); wave = 64 contiguous f4 -> 1 KiB/load.
//
// v3 change vs v2 (98 us dispatch): explicit P=16 register prefetch pipeline.
// v1->v2 showed per-CU streaming rate stuck at ~15 GB/s/CU (copy ubench:
// 24.6) and nearly insensitive to waves/CU -- the limiter is outstanding
// loads PER WAVE (VGPR_Count=28 => ~3-4 in flight, vmcnt stall every
// iteration). Fix: 16-deep rotating f4 buffer (64 VGPRs), fully unrolled
// with compile-time indices, warm-up+main fused into one 128-step stream so
// the pipeline never drains. Keeps L=64 / 512 blocks / 8 waves/CU and the
// XCD pinning (FETCH==input proved warm-up re-reads are L2/L3-absorbed).

using f4 = __attribute__((ext_vector_type(4))) float;

constexpr int Bn = 8;
constexpr int Tn = 4096;
constexpr int F4 = 256;        // 1024 floats / 4
constexpr int L  = 64;         // outputs per thread
constexpr int W  = 64;         // warm-up steps (0.9^64 ~ 1.18e-3)
constexpr int P  = 16;         // prefetch depth (64 VGPRs of buffer)
constexpr float A   = 0.9f;
constexpr float OMA = 0.1f;    // 1 - alpha

// Stream NSKIP+NSTORE timesteps through the EMA accumulator behind a P-deep
// register prefetch pipeline; emit stores for the last NSTORE steps.
// All control folds at compile time (full unroll, constant buffer indices).
template <int NSKIP, int NSTORE>
__device__ __forceinline__ void ema_stream(const f4* __restrict__ xs,
                                           f4* __restrict__ ys,
                                           float& ax, float& ay,
                                           float& az, float& aw) {
    constexpr int N = NSKIP + NSTORE;
    f4 buf[P];
    #pragma unroll
    for (int i = 0; i < P; ++i) buf[i] = xs[i * F4];
    #pragma unroll
    for (int i = 0; i < N; ++i) {
        f4 v = buf[i % P];                       // i%P is compile-time
        if (i + P < N) buf[i % P] = xs[(i + P) * F4];  // folds at compile time
        ax = fmaf(A, ax, OMA * v.x);
        ay = fmaf(A, ay, OMA * v.y);
        az = fmaf(A, az, OMA * v.z);
        aw = fmaf(A, aw, OMA * v.w);
        if (i >= NSKIP) {                        // folds at compile time
            f4 o;
            o.x = ax; o.y = ay; o.z = az; o.w = aw;
            __builtin_nontemporal_store(o, ys + (i - NSKIP) * F4);
        }
    }
}

__global__ __launch_bounds__(256) void ema_kernel(const f4* __restrict__ x,
                                                  f4* __restrict__ y) {
    const int tid          = threadIdx.x;
    const int lane_f       = tid & 63;        // f4 within group (wave-contig)
    const int chunk_in_blk = tid >> 6;        // 0..3 (wave-uniform)

    // XCD pinning: all 16 chunk-blocks of a stream p=(b,fg) share one XCD so
    // warm-up reads hit the L2 the previous chunk's main reads stream through.
    const int blk      = blockIdx.x;          // 0..511
    const int xcd      = blk & 7;
    const int slot     = blk >> 3;            // 0..63
    const int chunkgrp = slot & 15;           // 0..15
    const int p        = ((slot >> 4) << 3) | xcd;   // stream id 0..31
    const int fg       = p & 3;               // 4 f-groups
    const int b        = p >> 2;              // 8 batches

    const int chunk = chunkgrp * 4 + chunk_in_blk;   // 0..63
    const int f4i   = (fg << 6) + lane_f;            // 0..255
    const int t0    = chunk * L;

    const f4* __restrict__ xp = x + (size_t)b * Tn * F4 + f4i;
    f4*       __restrict__ yp = y + (size_t)b * Tn * F4 + f4i;

    float ax = 0.f, ay = 0.f, az = 0.f, aw = 0.f;
    f4* __restrict__ op = yp + (size_t)t0 * F4;

    if (chunk > 0) {   // wave-uniform branch
        ema_stream<W, L>(xp + (size_t)(t0 - W) * F4, op, ax, ay, az, aw);
    } else {
        ema_stream<0, L>(xp, op, ax, ay, az, aw);
    }
}

extern "C" void kernel_launch(void* const* d_in, const int* in_sizes, int n_in,
                              void* d_out, int out_size, void* d_ws, size_t ws_size,
                              hipStream_t stream) {
    const f4* x = (const f4*)d_in[0];
    f4*       y = (f4*)d_out;
    dim3 grid(Bn * 4 * 16);  // 512 blocks (8 b x 4 fg x 16 chunkgroups)
    dim3 block(256);
    ema_kernel<<<grid, block, 0, stream>>>(x, y);
}

// Round 3
// 243.907 us; speedup vs baseline: 1.0261x; 1.0002x over previous
//
#include <hip/hip_runtime.h>

// EMA along T for x[B=8, T=4096, F=1024] fp32.
// y_t = a*y_{t-1} + (1-a)*x_t, a=0.9, y_{-1}=0.
//
// Chunked scan with truncated warm-up (W=64; 0.9^64 ~ 1.2e-3 << 2.58e-2
// threshold).
//
// v4 change vs v3 (98 us dispatch): CONTIGUOUS STREAMS. v1->v3 established:
//  - traffic is compulsory (FETCH~input, WRITE~output), L2 absorbs warm-up
//  - BW stuck at ~16 GB/s/CU regardless of waves/CU (4 vs 8) or per-wave
//    pipeline depth => not latency-bound; request-QUALITY bound.
// Old layout: each wave = 1 KiB of F at fixed t, stepping t => 1 KiB bursts
// at 4 KiB stride, 2048 interleaved strided streams => DRAM row thrash at
// ~43% of copy-ubench efficiency.
// New layout: block = (b, chunk); its 256 threads span ALL of F (f4i=tid).
// The 4 waves at step t jointly cover one contiguous 4 KiB row; t advances
// sequentially => 256 blocks each streaming a contiguous 768 KiB read region
// and 512 KiB write region. Raw s_barrier every 8 steps keeps the 4 waves
// lockstep (no data dependency -- pure scheduling hint; does NOT drain
// vmcnt like __syncthreads would).
// chunk is now block-uniform; XCD pinning gives consecutive chunks of a
// stream the same L2 so warm-up re-reads stay L2-local.

using f4 = __attribute__((ext_vector_type(4))) float;

constexpr int Bn = 8;
constexpr int Tn = 4096;
constexpr int F4 = 256;        // 1024 floats / 4
constexpr int L  = 128;        // outputs per thread (32 chunks)
constexpr int W  = 64;         // warm-up steps (0.9^64 ~ 1.18e-3)
constexpr int P  = 16;         // prefetch depth
constexpr float A   = 0.9f;
constexpr float OMA = 0.1f;    // 1 - alpha

// Stream NSKIP+NSTORE timesteps through the EMA accumulator behind a P-deep
// register prefetch pipeline; emit stores for the last NSTORE steps.
// Raw s_barrier every 8 steps keeps the block's 4 waves adjacent so their
// combined access stays a contiguous 4 KiB/step stream.
template <int NSKIP, int NSTORE>
__device__ __forceinline__ void ema_stream(const f4* __restrict__ xs,
                                           f4* __restrict__ ys,
                                           float& ax, float& ay,
                                           float& az, float& aw) {
    constexpr int N = NSKIP + NSTORE;
    f4 buf[P];
    #pragma unroll
    for (int i = 0; i < P; ++i) buf[i] = xs[(size_t)i * F4];
    #pragma unroll
    for (int i = 0; i < N; ++i) {
        f4 v = buf[i % P];                       // i%P is compile-time
        if (i + P < N) buf[i % P] = xs[(size_t)(i + P) * F4];
        ax = fmaf(A, ax, OMA * v.x);
        ay = fmaf(A, ay, OMA * v.y);
        az = fmaf(A, az, OMA * v.z);
        aw = fmaf(A, aw, OMA * v.w);
        if (i >= NSKIP) {                        // folds at compile time
            f4 o;
            o.x = ax; o.y = ay; o.z = az; o.w = aw;
            __builtin_nontemporal_store(o, ys + (size_t)(i - NSKIP) * F4);
        }
        if ((i & 7) == 7) __builtin_amdgcn_s_barrier();  // lockstep hint
    }
}

__global__ __launch_bounds__(256) void ema_kernel(const f4* __restrict__ x,
                                                  f4* __restrict__ y) {
    // Block-uniform decode: 256 blocks = 8 XCD x 4 chunk-in-xcd x 8 b.
    // chunk = xcd*4 + g => chunks 4k..4k+3 share an XCD, so a chunk's
    // warm-up region (tail of chunk-1's main region) is in the same L2
    // for 3 of every 4 chunks.
    const int blk  = blockIdx.x;       // 0..255
    const int xcd  = blk & 7;
    const int idx  = blk >> 3;         // 0..31
    const int g    = idx & 3;          // 0..3
    const int b    = idx >> 2;         // 0..7
    const int chunk = (xcd << 2) | g;  // 0..31 (block-uniform)
    const int t0    = chunk * L;

    const int f4i = threadIdx.x;       // 0..255: block spans ALL of F

    const f4* __restrict__ xp = x + (size_t)b * Tn * F4 + f4i;
    f4*       __restrict__ yp = y + (size_t)b * Tn * F4 + f4i;

    float ax = 0.f, ay = 0.f, az = 0.f, aw = 0.f;
    f4* __restrict__ op = yp + (size_t)t0 * F4;

    if (chunk > 0) {   // block-uniform branch
        ema_stream<W, L>(xp + (size_t)(t0 - W) * F4, op, ax, ay, az, aw);
    } else {
        ema_stream<0, L>(xp, op, ax, ay, az, aw);
    }
}

extern "C" void kernel_launch(void* const* d_in, const int* in_sizes, int n_in,
                              void* d_out, int out_size, void* d_ws, size_t ws_size,
                              hipStream_t stream) {
    const f4* x = (const f4*)d_in[0];
    f4*       y = (f4*)d_out;
    dim3 grid(Bn * (Tn / L));  // 256 blocks (8 b x 32 chunks)
    dim3 block(256);
    ema_kernel<<<grid, block, 0, stream>>>(x, y);
}